// Round 16
// baseline (51.991 us; speedup 1.0000x reference)
//
#include <hip/hip_runtime.h>
#include <hip/hip_bf16.h>

// Problem constants
#define TT 2048
#define BB 4
#define CC 512
#define HH 16
#define KK 31
#define PP 15
#define MM (TT*BB)      // 8192 rows
#define NPAD 512

typedef __bf16 bf16x8 __attribute__((ext_vector_type(8)));
typedef float f32x4 __attribute__((ext_vector_type(4)));
typedef unsigned short ushort8 __attribute__((ext_vector_type(8)));
typedef unsigned short ushort4v __attribute__((ext_vector_type(4)));

__device__ __forceinline__ float bf2f(unsigned short u) {
    return __uint_as_float(((unsigned int)u) << 16);
}
__device__ __forceinline__ unsigned short f2bf(float f) {
    unsigned int x = __float_as_uint(f);
    x += 0x7fffu + ((x >> 16) & 1u);
    return (unsigned short)(x >> 16);
}

// ---------------------------------------------------------------------------
// weights-only cast (x is consumed fp32 by GEMM1 directly).
// 768 blocks: W1 / Wl (zero-padded to 512 rows) / W2.
// ---------------------------------------------------------------------------
__global__ __launch_bounds__(256) void cast_weights(const float* __restrict__ W1,
                                                    const float* __restrict__ Wl,
                                                    const float* __restrict__ W2,
                                                    unsigned short* __restrict__ W1b,
                                                    unsigned short* __restrict__ Wlb,
                                                    unsigned short* __restrict__ W2b) {
    const int b = blockIdx.x;
    const int i = (b & 255) * 1024 + threadIdx.x * 4;
    const float* src;
    unsigned short* dst;
    int n_src = 262144;
    if (b < 256)      { src = W1; dst = W1b; }
    else if (b < 512) { src = Wl; dst = Wlb; n_src = HH * KK * CC; }
    else              { src = W2; dst = W2b; }
    ushort4v o = {0, 0, 0, 0};
    if (i < n_src) {
        const float4 v = *(const float4*)&src[i];
        o[0] = f2bf(v.x); o[1] = f2bf(v.y); o[2] = f2bf(v.z); o[3] = f2bf(v.w);
    }
    *(ushort4v*)&dst[i] = o;
}

// ---------------------------------------------------------------------------
// bf16 MFMA GEMM-NT, 3-stage counted-vmcnt pipeline, 8 waves (R13 compute).
// C[m,n] = sum_k A[m,k]*B[n,k] (+bias[n]); K=512 (NT=8 x BK=64).
// 128x64 tile, 512 thr = 8 waves (4m x 2n), wave-tile 32x32.
// B: ALWAYS bf16 global_load_lds, pre-swizzled source (R13-proven).
// A: AF32=0 -> bf16 global_load_lds (R13-proven)            [GEMM2/3]
//    AF32=1 -> reg-staged fp32 -> cvt -> ds_write (R14-proven) [GEMM1: x]
// AF32=1 pipeline per iter kt:
//   {WRITEA_F(kt+1) [implicit vmcnt wait; in-order retire also clears
//    GLOADB(kt), which is strictly older]; LOADA_F(kt+2); lgkmcnt(0);
//    [vmcnt(0) iff last]; barrier; GLOADB(kt+2); compute(kt)}
// AF32=0 pipeline = R13 verbatim: {vmcnt(3)|0; barrier; STAGE3(kt+2); compute}.
// LDS 72 KB -> 2 blocks/CU. Swizzle slot^=(row&7) both sides.
// ---------------------------------------------------------------------------
#define GBM 128
#define GBN 64
#define GBK 64
#define KC  512
#define NT  8

#define PACK8(lo, hi, dst)                                                      \
    do { ushort8 o_;                                                            \
         o_[0] = f2bf((lo).x); o_[1] = f2bf((lo).y);                            \
         o_[2] = f2bf((lo).z); o_[3] = f2bf((lo).w);                            \
         o_[4] = f2bf((hi).x); o_[5] = f2bf((hi).y);                            \
         o_[6] = f2bf((hi).z); o_[7] = f2bf((hi).w);                            \
         *(ushort8*)(dst) = o_; } while (0)

#define GLOADB(kt, buf)                                                         \
    __builtin_amdgcn_global_load_lds(                                           \
        (const __attribute__((address_space(1))) void*)(gBg + (kt) * GBK),      \
        (__attribute__((address_space(3))) void*)(&Bs[buf][0] + wv * 512),      \
        16, 0, 0)

#define STAGE3(kt, buf)                                                         \
    do { const int k0_ = (kt) * GBK;                                            \
         _Pragma("unroll")                                                      \
         for (int j_ = 0; j_ < 2; ++j_)                                         \
             __builtin_amdgcn_global_load_lds(                                  \
                 (const __attribute__((address_space(1))) void*)(gAg[j_] + k0_),\
                 (__attribute__((address_space(3))) void*)(&As[buf][0] + (j_ * 512 + wv * 64) * 8), \
                 16, 0, 0);                                                     \
         GLOADB(kt, buf); } while (0)

#define LOADA_F(kt, d)                                                          \
    do { _Pragma("unroll")                                                      \
         for (int j_ = 0; j_ < 2; ++j_) {                                       \
             aLo[d][j_] = *(const float4*)(gAf[j_] + (kt) * GBK);               \
             aHi[d][j_] = *(const float4*)(gAf[j_] + (kt) * GBK + 4);           \
         } } while (0)

#define WRITEA_F(kt, d)                                                         \
    do { _Pragma("unroll")                                                      \
         for (int j_ = 0; j_ < 2; ++j_)                                         \
             PACK8(aLo[d][j_], aHi[d][j_],                                      \
                   &As[(kt) % 3][rA[j_] * 64 + psA[j_] * 8]); } while (0)

#define COMPUTE(kt)                                                             \
    do { const int cb_ = (kt) % 3;                                              \
         bf16x8 af[2][2], bfv[2][2];                                            \
         _Pragma("unroll")                                                      \
         for (int mi = 0; mi < 2; ++mi)                                         \
             _Pragma("unroll")                                                  \
             for (int ks = 0; ks < 2; ++ks)                                     \
                 af[mi][ks] = *(const bf16x8*)&As[cb_][offA[mi][ks]];           \
         _Pragma("unroll")                                                      \
         for (int ni = 0; ni < 2; ++ni)                                         \
             _Pragma("unroll")                                                  \
             for (int ks = 0; ks < 2; ++ks)                                     \
                 bfv[ni][ks] = *(const bf16x8*)&Bs[cb_][offB[ni][ks]];          \
         _Pragma("unroll")                                                      \
         for (int mi = 0; mi < 2; ++mi)                                         \
             _Pragma("unroll")                                                  \
             for (int ni = 0; ni < 2; ++ni)                                     \
                 _Pragma("unroll")                                              \
                 for (int ks = 0; ks < 2; ++ks)                                 \
                     acc[mi][ni] = __builtin_amdgcn_mfma_f32_16x16x32_bf16(     \
                         af[mi][ks], bfv[ni][ks], acc[mi][ni], 0, 0, 0);        \
    } while (0)

template<int AF32, int OUT_BF16>
__global__ __launch_bounds__(512, 4) void gemm_nt_mfma(const void* __restrict__ Aptr,
                                                       const unsigned short* __restrict__ Bb,
                                                       const float* __restrict__ bias,
                                                       void* __restrict__ Cout,
                                                       int N, int nn) {
    __shared__ short As[3][GBM * GBK];   // 3 x 16 KB
    __shared__ short Bs[3][GBN * GBK];   // 3 x 8 KB

    const int tid = threadIdx.x;
    const int l   = tid & 63;
    const int wv  = tid >> 6;      // wave 0..7
    const int wr  = wv >> 1;       // 0..3 -> 32 rows
    const int wc  = wv & 1;        // 0..1 -> 32 cols

    // chunked XCD swizzle (gridDim.x % 8 == 0)
    const int s  = (blockIdx.x & 7) * (gridDim.x >> 3) + (blockIdx.x >> 3);
    const int bm = (s / nn) * GBM;
    const int bn = (s % nn) * GBN;

    // B staging (bf16 gload, pre-swizzled source): 64 rows x 8 slots, 1/thread
    const int rB  = tid >> 3;
    const int slB = (tid & 7) ^ (rB & 7);
    const unsigned short* gBg = Bb + (size_t)(bn + rB) * KC + slB * 8;

    // A staging setup
    int rA[2], psA[2];
    const float* gAf[2];
    const unsigned short* gAg[2];
    #pragma unroll
    for (int j = 0; j < 2; ++j) {
        const int slot = j * 512 + tid;
        const int r = slot >> 3;
        const int p = slot & 7;
        rA[j] = r; psA[j] = p ^ (r & 7);
        gAf[j] = (const float*)Aptr + (size_t)(bm + r) * KC + p * 8;
        gAg[j] = (const unsigned short*)Aptr + (size_t)(bm + r) * KC + (p ^ (r & 7)) * 8;
    }
    float4 aLo[2][2], aHi[2][2];

    f32x4 acc[2][2] = {};

    const int lr = l & 15;
    const int ls = l >> 4;
    int offA[2][2], offB[2][2];
    #pragma unroll
    for (int mi = 0; mi < 2; ++mi) {
        const int r = wr * 32 + mi * 16 + lr;
        #pragma unroll
        for (int ks = 0; ks < 2; ++ks)
            offA[mi][ks] = r * 64 + (((ks * 4 + ls) ^ (r & 7)) * 8);
    }
    #pragma unroll
    for (int ni = 0; ni < 2; ++ni) {
        const int r = wc * 32 + ni * 16 + lr;
        #pragma unroll
        for (int ks = 0; ks < 2; ++ks)
            offB[ni][ks] = r * 64 + (((ks * 4 + ls) ^ (r & 7)) * 8);
    }

    if constexpr (AF32) {
        // ---- GEMM1: reg-staged fp32 A + bf16 gload B ----
        LOADA_F(0, 0); GLOADB(0, 0);
        LOADA_F(1, 1); GLOADB(1, 1);
        WRITEA_F(0, 0);

        #pragma unroll
        for (int kt = 0; kt < NT; ++kt) {
            // implicit vmcnt wait here (A regs) also retires older GLOADB(kt)
            if (kt + 1 < NT) WRITEA_F(kt + 1, (kt + 1) & 1);
            if (kt + 2 < NT) LOADA_F(kt + 2, (kt + 2) & 1);
            asm volatile("s_waitcnt lgkmcnt(0)" ::: "memory");
            if (kt == NT - 1) asm volatile("s_waitcnt vmcnt(0)" ::: "memory");
            __builtin_amdgcn_s_barrier();
            asm volatile("" ::: "memory");
            if (kt + 2 < NT) GLOADB(kt + 2, (kt + 2) % 3);
            COMPUTE(kt);
        }
    } else {
        // ---- GEMM2/3: R13-verbatim gload pipeline (3 loads/thread/stage) ----
        STAGE3(0, 0);
        STAGE3(1, 1);

        #pragma unroll
        for (int kt = 0; kt < NT; ++kt) {
            if (kt < NT - 1) asm volatile("s_waitcnt vmcnt(3)" ::: "memory");
            else             asm volatile("s_waitcnt vmcnt(0)" ::: "memory");
            __builtin_amdgcn_s_barrier();
            if (kt + 2 < NT) STAGE3(kt + 2, (kt + 2) % 3);
            COMPUTE(kt);
        }
    }

    // C/D layout (m89): col = lane&15, row = (lane>>4)*4 + j
    #pragma unroll
    for (int mi = 0; mi < 2; ++mi) {
        const int row0 = bm + wr * 32 + mi * 16 + ls * 4;
        #pragma unroll
        for (int ni = 0; ni < 2; ++ni) {
            const int col = bn + wc * 32 + ni * 16 + lr;
            const float bv = bias ? bias[col] : 0.0f;
            #pragma unroll
            for (int j = 0; j < 4; ++j) {
                const float v = acc[mi][ni][j] + bv;
                if (OUT_BF16)
                    ((unsigned short*)Cout)[(size_t)(row0 + j) * N + col] = f2bf(v);
                else
                    ((float*)Cout)[(size_t)(row0 + j) * N + col] = v;
            }
        }
    }
}

// ---------------------------------------------------------------------------
// Fused softmax + rolling dynamic conv (proven R9 version).
// Block = (4 consecutive t, one b), 64 threads (1 wave).
// ---------------------------------------------------------------------------
__global__ __launch_bounds__(64) void dynconv_fused(const unsigned short* __restrict__ hb,
                                                    const unsigned short* __restrict__ lgb,
                                                    unsigned short* __restrict__ cvb) {
    __shared__ float w_s[64][33];

    const int bid = blockIdx.x;
    const int u   = (bid & 7) * 256 + (bid >> 3);   // 2048 % 8 == 0, bijective
    const int tg  = u >> 2;
    const int b   = u & 3;
    const int t0  = tg * 4;
    const int tid = threadIdx.x;

    {
        const int dt = tid >> 4, hd = tid & 15;
        const unsigned short* lp = lgb + (size_t)((t0 + dt) * BB + b) * NPAD + hd * KK;
        float e[KK];
        float mx = -1e30f;
        #pragma unroll
        for (int k = 0; k < KK; ++k) { e[k] = bf2f(lp[k]); mx = fmaxf(mx, e[k]); }
        float sm = 0.f;
        #pragma unroll
        for (int k = 0; k < KK; ++k) { e[k] = __expf(e[k] - mx); sm += e[k]; }
        const float inv = 1.f / sm;
        #pragma unroll
        for (int k = 0; k < KK; ++k) w_s[tid][k] = e[k] * inv;
    }
    __syncthreads();

    const int c0 = tid * 8;
    const int hd = tid >> 2;
    float acc[4][8] = {};
    #pragma unroll
    for (int j = 0; j < 34; ++j) {
        const int tt = t0 - PP + j;
        if ((unsigned)tt >= TT) continue;
        const ushort8 hv = *(const ushort8*)&hb[(size_t)((tt * BB + b) * CC) + c0];
        float hf[8];
        #pragma unroll
        for (int cc = 0; cc < 8; ++cc) hf[cc] = bf2f(hv[cc]);
        #pragma unroll
        for (int dt = 0; dt < 4; ++dt) {
            const int k = j - dt;
            if (k < 0 || k >= KK) continue;
            const float wk = w_s[dt * 16 + hd][k];
            #pragma unroll
            for (int cc = 0; cc < 8; ++cc) acc[dt][cc] = fmaf(hf[cc], wk, acc[dt][cc]);
        }
    }
    #pragma unroll
    for (int dt = 0; dt < 4; ++dt) {
        ushort8 o;
        #pragma unroll
        for (int cc = 0; cc < 8; ++cc) o[cc] = f2bf(acc[dt][cc]);
        *(ushort8*)&cvb[(size_t)(((t0 + dt) * BB + b) * CC) + c0] = o;
    }
}

extern "C" void kernel_launch(void* const* d_in, const int* in_sizes, int n_in,
                              void* d_out, int out_size, void* d_ws, size_t ws_size,
                              hipStream_t stream) {
    const float* x  = (const float*)d_in[0];
    const float* W1 = (const float*)d_in[1];
    const float* b1 = (const float*)d_in[2];
    const float* Wl = (const float*)d_in[3];
    const float* W2 = (const float*)d_in[4];
    const float* b2 = (const float*)d_in[5];
    float* out = (float*)d_out;

    // workspace: bf16 intermediates + bf16 weights
    unsigned short* hb  = (unsigned short*)d_ws;             // 8 MB
    unsigned short* cvb = hb  + (size_t)MM * CC;             // 8 MB
    unsigned short* lgb = cvb + (size_t)MM * CC;             // 8 MB
    unsigned short* W1b = lgb + (size_t)MM * CC;             // 0.5 MB
    unsigned short* Wlb = W1b + (size_t)CC * CC;             // 0.5 MB (padded)
    unsigned short* W2b = Wlb + (size_t)NPAD * CC;           // 0.5 MB

    // weights-only cast (x is consumed fp32 by GEMM1)
    cast_weights<<<768, 256, 0, stream>>>(W1, Wl, W2, W1b, Wlb, W2b);

    const int nblk = (MM / GBM) * (CC / GBN);   // 64 * 8 = 512

    // 1) h = x @ W1^T + b1   (A: x fp32 reg-staged; B: W1b bf16 gload; bf16 out)
    gemm_nt_mfma<1, 1><<<nblk, 512, 0, stream>>>(x, W1b, b1, hb, CC, CC / GBN);
    // 2) logits = h @ Wl^T   (R13 path; bf16 out, padded N)
    gemm_nt_mfma<0, 1><<<nblk, 512, 0, stream>>>(hb, Wlb, nullptr, lgb, NPAD, NPAD / GBN);
    // 3+4) fused softmax + rolling dynamic conv (bf16 out)
    dynconv_fused<<<TT * BB / 4, 64, 0, stream>>>(hb, lgb, cvb);
    // 5) out = cv @ W2^T + b2  (R13 path; fp32 out)
    gemm_nt_mfma<0, 0><<<nblk, 512, 0, stream>>>(cvb, W2b, b2, out, CC, CC / GBN);
}

// Round 17
// 50.482 us; speedup vs baseline: 1.0299x; 1.0299x over previous
//
#include <hip/hip_runtime.h>
#include <hip/hip_bf16.h>

// Problem constants
#define TT 2048
#define BB 4
#define CC 512
#define HH 16
#define KK 31
#define PP 15
#define MM (TT*BB)      // 8192 rows
#define NPAD 512        // HK=496 padded to 512 (pad rows of Wl are zero)

typedef __bf16 bf16x8 __attribute__((ext_vector_type(8)));
typedef float f32x4 __attribute__((ext_vector_type(4)));
typedef unsigned short ushort8 __attribute__((ext_vector_type(8)));
typedef unsigned short ushort4v __attribute__((ext_vector_type(4)));

__device__ __forceinline__ float bf2f(unsigned short u) {
    return __uint_as_float(((unsigned int)u) << 16);
}
__device__ __forceinline__ unsigned short f2bf(float f) {
    unsigned int x = __float_as_uint(f);
    x += 0x7fffu + ((x >> 16) & 1u);
    return (unsigned short)(x >> 16);
}

// ---------------------------------------------------------------------------
// single cast dispatch: blocks 0..4095 cast x (1024 elems each);
// blocks 4096..4863 cast W1/Wl/W2 (Wl zero-padded to 512 rows).
// ---------------------------------------------------------------------------
__global__ __launch_bounds__(256) void cast_all(const float* __restrict__ x,
                                                const float* __restrict__ W1,
                                                const float* __restrict__ Wl,
                                                const float* __restrict__ W2,
                                                unsigned short* __restrict__ xb,
                                                unsigned short* __restrict__ W1b,
                                                unsigned short* __restrict__ Wlb,
                                                unsigned short* __restrict__ W2b) {
    const int b = blockIdx.x;
    if (b < 4096) {
        const int i = b * 1024 + threadIdx.x * 4;
        const float4 v = *(const float4*)&x[i];
        ushort4v o = { f2bf(v.x), f2bf(v.y), f2bf(v.z), f2bf(v.w) };
        *(ushort4v*)&xb[i] = o;
        return;
    }
    const int bb = b - 4096;                 // 0..767
    const int i = (bb & 255) * 1024 + threadIdx.x * 4;
    const float* src;
    unsigned short* dst;
    int n_src = 262144;
    if (bb < 256)      { src = W1; dst = W1b; }
    else if (bb < 512) { src = Wl; dst = Wlb; n_src = HH * KK * CC; }
    else               { src = W2; dst = W2b; }
    ushort4v o = {0, 0, 0, 0};
    if (i < n_src) {
        const float4 v = *(const float4*)&src[i];
        o[0] = f2bf(v.x); o[1] = f2bf(v.y); o[2] = f2bf(v.z); o[3] = f2bf(v.w);
    }
    *(ushort4v*)&dst[i] = o;
}

// ---------------------------------------------------------------------------
// bf16 MFMA GEMM-NT, 3-stage counted-vmcnt pipeline, 8 waves (R13 config =
// proven 50.36 us total) + T5 s_setprio around the MFMA cluster.
// C[m,n] = sum_k A[m,k]*B[n,k] (+bias[n]); K fixed 512 (NT=8 x BK=64).
// 128x64 tile, 512 thr = 8 waves (4m x 2n), wave-tile 32x32.
// LDS 3*(16+8)=72 KB -> 2 blocks/CU -> 16 waves/CU = 4 waves/SIMD.
// Per iter kt: {vmcnt(3); s_barrier; STAGE(kt+2); setprio(1) MFMA setprio(0)}.
// STAGE = 3 loads/thread (2 A rounds + 1 B round). Swizzle slot^=(row&7).
// ---------------------------------------------------------------------------
#define GBM 128
#define GBN 64
#define GBK 64
#define KC  512
#define NT  8

#define STAGE(kt, buf)                                                                             \
    do {                                                                                           \
        const int k0_ = (kt) * GBK;                                                                \
        _Pragma("unroll")                                                                          \
        for (int j = 0; j < 2; ++j)                                                                \
            __builtin_amdgcn_global_load_lds(                                                      \
                (const __attribute__((address_space(1))) void*)(gA[j] + k0_),                      \
                (__attribute__((address_space(3))) void*)(&As[buf][0] + (j * 512 + wv * 64) * 8),  \
                16, 0, 0);                                                                         \
        __builtin_amdgcn_global_load_lds(                                                          \
            (const __attribute__((address_space(1))) void*)(gB0 + k0_),                            \
            (__attribute__((address_space(3))) void*)(&Bs[buf][0] + wv * 64 * 8),                  \
            16, 0, 0);                                                                             \
    } while (0)

template<bool OUT_BF16>
__global__ __launch_bounds__(512, 4) void gemm_nt_mfma(const unsigned short* __restrict__ A,
                                                       const unsigned short* __restrict__ B,
                                                       const float* __restrict__ bias,
                                                       void* __restrict__ Cout,
                                                       int N, int nn) {
    __shared__ short As[3][GBM * GBK];   // 3 x 16 KB
    __shared__ short Bs[3][GBN * GBK];   // 3 x 8 KB

    const int tid = threadIdx.x;
    const int l   = tid & 63;
    const int wv  = tid >> 6;      // wave 0..7
    const int wr  = wv >> 1;       // wave row (0..3) -> 32 rows each
    const int wc  = wv & 1;        // wave col (0..1) -> 32 cols each

    // chunked XCD swizzle; consecutive s share A panel in the XCD's L2
    const int s  = (blockIdx.x & 7) * (gridDim.x >> 3) + (blockIdx.x >> 3);
    const int bm = (s / nn) * GBM;
    const int bn = (s % nn) * GBN;

    // Staging: A tile 128 rows x 8 slots(16B) = 1024 slots = 2 rounds x 512thr;
    // B tile 64 x 8 = 512 slots = 1 round. Linear LDS dest; source slot
    // pre-swizzled slot' = slot ^ (row&7) (involution, matches ds_read).
    const unsigned short* gA[2];
    #pragma unroll
    for (int j = 0; j < 2; ++j) {
        const int slot = j * 512 + tid;
        const int r  = slot >> 3;
        const int sl = (slot & 7) ^ (r & 7);
        gA[j] = A + (size_t)(bm + r) * KC + sl * 8;
    }
    const int rB  = tid >> 3;
    const int slB = (tid & 7) ^ (rB & 7);
    const unsigned short* gB0 = B + (size_t)(bn + rB) * KC + slB * 8;

    f32x4 acc[2][2] = {};

    const int lr = l & 15;     // fragment row-within-16
    const int ls = l >> 4;     // k-slot (8 bf16 each)
    int offA[2][2], offB[2][2];
    #pragma unroll
    for (int mi = 0; mi < 2; ++mi) {
        const int r = wr * 32 + mi * 16 + lr;
        #pragma unroll
        for (int ks = 0; ks < 2; ++ks)
            offA[mi][ks] = r * 64 + (((ks * 4 + ls) ^ (r & 7)) * 8);
    }
    #pragma unroll
    for (int ni = 0; ni < 2; ++ni) {
        const int r = wc * 32 + ni * 16 + lr;
        #pragma unroll
        for (int ks = 0; ks < 2; ++ks)
            offB[ni][ks] = r * 64 + (((ks * 4 + ls) ^ (r & 7)) * 8);
    }

    // prologue: stage tiles 0,1 (6 loads in flight per thread-slot)
    STAGE(0, 0);
    STAGE(1, 1);

    #pragma unroll
    for (int kt = 0; kt < NT; ++kt) {
        // (a) tile kt resident; tile kt+1's 3 loads stay in flight
        if (kt < NT - 1) asm volatile("s_waitcnt vmcnt(3)" ::: "memory");
        else             asm volatile("s_waitcnt vmcnt(0)" ::: "memory");
        // (b) all waves: tile kt loaded everywhere, compute(kt-1) done
        __builtin_amdgcn_s_barrier();
        // (c) prefetch tile kt+2 (overwrites buf[(kt-1)%3], safe post-barrier)
        if (kt + 2 < NT) STAGE(kt + 2, (kt + 2) % 3);

        // (d) compute on buf kt%3
        const int cb = kt % 3;
        bf16x8 af[2][2], bfv[2][2];
        #pragma unroll
        for (int mi = 0; mi < 2; ++mi)
            #pragma unroll
            for (int ks = 0; ks < 2; ++ks)
                af[mi][ks] = *(const bf16x8*)&As[cb][offA[mi][ks]];
        #pragma unroll
        for (int ni = 0; ni < 2; ++ni)
            #pragma unroll
            for (int ks = 0; ks < 2; ++ks)
                bfv[ni][ks] = *(const bf16x8*)&Bs[cb][offB[ni][ks]];

        // T5: boost this wave while it drains its MFMA cluster
        __builtin_amdgcn_s_setprio(1);
        #pragma unroll
        for (int mi = 0; mi < 2; ++mi)
            #pragma unroll
            for (int ni = 0; ni < 2; ++ni)
                #pragma unroll
                for (int ks = 0; ks < 2; ++ks)
                    acc[mi][ni] = __builtin_amdgcn_mfma_f32_16x16x32_bf16(af[mi][ks], bfv[ni][ks], acc[mi][ni], 0, 0, 0);
        __builtin_amdgcn_s_setprio(0);
    }

    // C/D layout (m89): col = lane&15, row = (lane>>4)*4 + j
    #pragma unroll
    for (int mi = 0; mi < 2; ++mi) {
        const int row0 = bm + wr * 32 + mi * 16 + ls * 4;
        #pragma unroll
        for (int ni = 0; ni < 2; ++ni) {
            const int col = bn + wc * 32 + ni * 16 + lr;
            const float bv = bias ? bias[col] : 0.0f;
            #pragma unroll
            for (int j = 0; j < 4; ++j) {
                const float v = acc[mi][ni][j] + bv;
                if (OUT_BF16)
                    ((unsigned short*)Cout)[(size_t)(row0 + j) * N + col] = f2bf(v);
                else
                    ((float*)Cout)[(size_t)(row0 + j) * N + col] = v;
            }
        }
    }
}

// ---------------------------------------------------------------------------
// Fused softmax + rolling dynamic conv (proven R9 version).
// Block = (4 consecutive t, one b), 64 threads (1 wave).
// ---------------------------------------------------------------------------
__global__ __launch_bounds__(64) void dynconv_fused(const unsigned short* __restrict__ hb,
                                                    const unsigned short* __restrict__ lgb,
                                                    unsigned short* __restrict__ cvb) {
    __shared__ float w_s[64][33];

    const int bid = blockIdx.x;
    const int u   = (bid & 7) * 256 + (bid >> 3);   // 2048 % 8 == 0, bijective
    const int tg  = u >> 2;
    const int b   = u & 3;
    const int t0  = tg * 4;
    const int tid = threadIdx.x;

    {
        const int dt = tid >> 4, hd = tid & 15;
        const unsigned short* lp = lgb + (size_t)((t0 + dt) * BB + b) * NPAD + hd * KK;
        float e[KK];
        float mx = -1e30f;
        #pragma unroll
        for (int k = 0; k < KK; ++k) { e[k] = bf2f(lp[k]); mx = fmaxf(mx, e[k]); }
        float sm = 0.f;
        #pragma unroll
        for (int k = 0; k < KK; ++k) { e[k] = __expf(e[k] - mx); sm += e[k]; }
        const float inv = 1.f / sm;
        #pragma unroll
        for (int k = 0; k < KK; ++k) w_s[tid][k] = e[k] * inv;
    }
    __syncthreads();

    const int c0 = tid * 8;
    const int hd = tid >> 2;
    float acc[4][8] = {};
    #pragma unroll
    for (int j = 0; j < 34; ++j) {
        const int tt = t0 - PP + j;
        if ((unsigned)tt >= TT) continue;
        const ushort8 hv = *(const ushort8*)&hb[(size_t)((tt * BB + b) * CC) + c0];
        float hf[8];
        #pragma unroll
        for (int cc = 0; cc < 8; ++cc) hf[cc] = bf2f(hv[cc]);
        #pragma unroll
        for (int dt = 0; dt < 4; ++dt) {
            const int k = j - dt;
            if (k < 0 || k >= KK) continue;
            const float wk = w_s[dt * 16 + hd][k];
            #pragma unroll
            for (int cc = 0; cc < 8; ++cc) acc[dt][cc] = fmaf(hf[cc], wk, acc[dt][cc]);
        }
    }
    #pragma unroll
    for (int dt = 0; dt < 4; ++dt) {
        ushort8 o;
        #pragma unroll
        for (int cc = 0; cc < 8; ++cc) o[cc] = f2bf(acc[dt][cc]);
        *(ushort8*)&cvb[(size_t)(((t0 + dt) * BB + b) * CC) + c0] = o;
    }
}

extern "C" void kernel_launch(void* const* d_in, const int* in_sizes, int n_in,
                              void* d_out, int out_size, void* d_ws, size_t ws_size,
                              hipStream_t stream) {
    const float* x  = (const float*)d_in[0];
    const float* W1 = (const float*)d_in[1];
    const float* b1 = (const float*)d_in[2];
    const float* Wl = (const float*)d_in[3];
    const float* W2 = (const float*)d_in[4];
    const float* b2 = (const float*)d_in[5];
    float* out = (float*)d_out;

    // workspace layout (all bf16 except out)
    unsigned short* xb  = (unsigned short*)d_ws;             // 8 MB
    unsigned short* hb  = xb  + (size_t)MM * CC;             // 8 MB
    unsigned short* cvb = hb  + (size_t)MM * CC;             // 8 MB
    unsigned short* W1b = cvb + (size_t)MM * CC;             // 0.5 MB
    unsigned short* Wlb = W1b + (size_t)CC * CC;             // 0.5 MB (padded)
    unsigned short* W2b = Wlb + (size_t)NPAD * CC;           // 0.5 MB
    unsigned short* lgb = W2b + (size_t)CC * CC;             // 8 MB bf16 logits

    // single cast dispatch (x + all weights)
    cast_all<<<4096 + 768, 256, 0, stream>>>(x, W1, Wl, W2, xb, W1b, Wlb, W2b);

    const int nblk = (MM / GBM) * (CC / GBN);   // 64 * 8 = 512

    // 1) h = x @ W1^T + b1   (bf16 out)
    gemm_nt_mfma<true><<<nblk, 512, 0, stream>>>(xb, W1b, b1, hb, CC, CC / GBN);
    // 2) logits = h @ Wl^T   (bf16 out, padded N)
    gemm_nt_mfma<true><<<nblk, 512, 0, stream>>>(hb, Wlb, nullptr, lgb, NPAD, NPAD / GBN);
    // 3+4) fused softmax + rolling dynamic conv (bf16 out)
    dynconv_fused<<<TT * BB / 4, 64, 0, stream>>>(hb, lgb, cvb);
    // 5) out = cv @ W2^T + b2  (fp32 out)
    gemm_nt_mfma<false><<<nblk, 512, 0, stream>>>(cvb, W2b, b2, out, CC, CC / GBN);
}